// Round 10
// baseline (84.094 us; speedup 1.0000x reference)
//
#include <hip/hip_runtime.h>
#include <math.h>

typedef float vf4 __attribute__((ext_vector_type(4)));

#define T_CHUNK 8   // t-rows per score block

__device__ __forceinline__ float wave_reduce_sum(float v) {
    #pragma unroll
    for (int off = 32; off > 0; off >>= 1)
        v += __shfl_xor(v, off, 64);
    return v;
}

// fast tanh: tanh(x) = 1 - 2/(exp(2x)+1); exp via v_exp, recip via v_rcp
__device__ __forceinline__ float fast_tanh(float x) {
    float e = __expf(2.0f * x);
    return 1.0f - 2.0f * __builtin_amdgcn_rcpf(e + 1.0f);
}

// Kernel 1: rec[b*H + h] = dot(rnn_state[b,:], W_rec[h,:])
__global__ void rec_kernel(const float* __restrict__ rnn,
                           const float* __restrict__ Wrec,
                           float* __restrict__ rec,
                           int B, int H, int R) {
    int w    = (blockIdx.x * blockDim.x + threadIdx.x) >> 6;
    int lane = threadIdx.x & 63;
    int nOut = B * H;
    if (w >= nOut) return;
    int b = w / H;
    int h = w - b * H;
    const float* xr = rnn  + (size_t)b * R;
    const float* wr = Wrec + (size_t)h * R;
    float acc = 0.f;
    for (int r = lane * 4; r < R; r += 256) {
        vf4 a = *(const vf4*)(xr + r);
        vf4 c = *(const vf4*)(wr + r);
        acc += a.x * c.x + a.y * c.y + a.z * c.z + a.w * c.w;
    }
    acc = wave_reduce_sum(acc);
    if (lane == 0) rec[w] = acc;
}

// Kernel 2: SEQUENTIAL-STREAM score. Block (512 thr, 8 waves) owns t-range
// [blockIdx*8, +8) x ALL 32 b. Wave wi covers b in [4wi, 4wi+4): per t-row it
// issues 8 contiguous 1KB float4 loads (8KB slice); the block as a whole
// streams its 512KB of enc in pure sequential order. rec fragments for the
// wave's 4 b's live in 8 vf4 registers. 7-shfl batched reduce per t.
// The block's 8x32 score tile is built in LDS; mask+bias added; scores
// written (T,B) coalesced; per-chunk partial softmax stats (max, expsum)
// emitted directly -- no separate stats kernel.
__global__ void score_kernel(const float* __restrict__ enc,
                             const float* __restrict__ mask,
                             const float* __restrict__ rec,
                             const float* __restrict__ wsc,
                             const float* __restrict__ bsc,
                             float* __restrict__ scores,  // (T,B)
                             float* __restrict__ pm,      // (NCH,B)
                             float* __restrict__ ps,      // (NCH,B)
                             int T, int B, int H) {
    const int tid  = threadIdx.x;
    const int wi   = tid >> 6;         // 0..7
    const int lane = tid & 63;
    const int t0   = blockIdx.x * T_CHUNK;
    const int b0   = wi * 4;

    __shared__ float sc_lds[T_CHUNK][32];

    // invariant operands
    vf4 w0 = *(const vf4*)(wsc + lane * 4);
    vf4 w1 = *(const vf4*)(wsc + 256 + lane * 4);
    vf4 rr[8];
    #pragma unroll
    for (int j = 0; j < 8; ++j)
        rr[j] = *(const vf4*)(rec + (size_t)(b0 + (j >> 1)) * H
                                   + ((j & 1) << 8) + lane * 4);
    const float bias = bsc[0];

    for (int ti = 0; ti < T_CHUNK; ++ti) {
        const float* rowp = enc + ((size_t)(t0 + ti) * B + b0) * H;
        float a[4] = {0.f, 0.f, 0.f, 0.f};
        #pragma unroll
        for (int j = 0; j < 8; ++j) {
            vf4 e  = *(const vf4*)(rowp + j * 256 + lane * 4);
            vf4 rv = rr[j];
            vf4 wv = (j & 1) ? w1 : w0;
            float p;
            p  = wv.x * fast_tanh(e.x + rv.x);
            p += wv.y * fast_tanh(e.y + rv.y);
            p += wv.z * fast_tanh(e.z + rv.z);
            p += wv.w * fast_tanh(e.w + rv.w);
            a[j >> 1] += p;
        }
        // batched tree-reduce of 4 rows: fold lane bits 0..1, then butterflies
        #pragma unroll
        for (int s = 0; s < 2; ++s) {
            const int bit = 1 << s;
            #pragma unroll
            for (int i = 0; i < (4 >> (s + 1)); ++i) {
                float sent = (lane & bit) ? a[2 * i]     : a[2 * i + 1];
                float keep = (lane & bit) ? a[2 * i + 1] : a[2 * i];
                a[i] = keep + __shfl_xor(sent, bit, 64);
            }
        }
        a[0] += __shfl_xor(a[0], 4, 64);
        a[0] += __shfl_xor(a[0], 8, 64);
        a[0] += __shfl_xor(a[0], 16, 64);
        a[0] += __shfl_xor(a[0], 32, 64);
        if (lane < 4) sc_lds[ti][b0 + lane] = a[0] + bias;
    }
    __syncthreads();

    // phase 2: add mask, write scores (T,B) coalesced, refresh LDS
    if (tid < T_CHUNK * 32) {
        const int tl = tid >> 5, b = tid & 31;
        float v = sc_lds[tl][b] + mask[(size_t)(t0 + tl) * B + b];
        scores[(size_t)(t0 + tl) * B + b] = v;
        sc_lds[tl][b] = v;
    }
    __syncthreads();

    // phase 3: per-b partial stats over this chunk's T_CHUNK rows
    if (tid < 32) {
        float m = -INFINITY;
        #pragma unroll
        for (int tl = 0; tl < T_CHUNK; ++tl)
            m = fmaxf(m, sc_lds[tl][tid]);
        float s = 0.f;
        #pragma unroll
        for (int tl = 0; tl < T_CHUNK; ++tl)
            s += __expf(sc_lds[tl][tid] - m);
        pm[(size_t)blockIdx.x * 32 + tid] = m;
        ps[(size_t)blockIdx.x * 32 + tid] = s;
    }
}

// Kernel 3: finalize. Each block (256 thr) redundantly merges the NCH
// per-chunk partials (8 slices x 32 b, two LDS rounds), then normalizes its
// 64-t x 32-b range fully coalesced in (T,B) -- no transpose needed.
__global__ void finalize_kernel(const float* __restrict__ scores, // (T,B)
                                const float* __restrict__ pm,
                                const float* __restrict__ ps,
                                float* __restrict__ out,
                                int T, int B, int NCH) {
    __shared__ float red[8][32];
    __shared__ float Ml[32], Sl[32];
    const int tid = threadIdx.x;
    const int b   = tid & 31;
    const int sl  = tid >> 5;            // 0..7
    const int cps = NCH / 8;             // chunks per slice

    float m = -INFINITY;
    for (int c = sl * cps; c < (sl + 1) * cps; ++c)
        m = fmaxf(m, pm[(size_t)c * 32 + b]);
    red[sl][b] = m;
    __syncthreads();
    if (tid < 32) {
        float M = -INFINITY;
        #pragma unroll
        for (int s = 0; s < 8; ++s) M = fmaxf(M, red[s][tid]);
        Ml[tid] = M;
    }
    __syncthreads();
    const float M = Ml[b];
    float s = 0.f;
    for (int c = sl * cps; c < (sl + 1) * cps; ++c)
        s += ps[(size_t)c * 32 + b] * __expf(pm[(size_t)c * 32 + b] - M);
    red[sl][b] = s;
    __syncthreads();
    if (tid < 32) {
        float S = 0.f;
        #pragma unroll
        for (int s2 = 0; s2 < 8; ++s2) S += red[s2][tid];
        Sl[tid] = 1.0f / S;
    }
    __syncthreads();
    const float Sinv = Sl[b];

    const int t0 = blockIdx.x * 64;
    #pragma unroll
    for (int i = 0; i < 8; ++i) {
        int t = t0 + i * 8 + sl;
        float x = scores[(size_t)t * B + b];
        out[(size_t)t * B + b] = __expf(x - M) * Sinv;
    }
}

extern "C" void kernel_launch(void* const* d_in, const int* in_sizes, int n_in,
                              void* d_out, int out_size, void* d_ws, size_t ws_size,
                              hipStream_t stream) {
    const float* enc  = (const float*)d_in[0];  // (T,B,H)
    const float* mask = (const float*)d_in[1];  // (T,B)
    const float* rnn  = (const float*)d_in[2];  // (B,R)
    // d_in[3] = prev_att_weights, unused by the reference
    const float* Wrec = (const float*)d_in[4];  // (H,R)
    const float* wsc  = (const float*)d_in[5];  // (H,)
    const float* bsc  = (const float*)d_in[6];  // (1,)

    const int H = in_sizes[5];
    const int R = in_sizes[4] / H;
    const int B = in_sizes[2] / R;
    const int T = in_sizes[1] / B;
    const int NCH = T / T_CHUNK;

    float* rec    = (float*)d_ws;                 // B*H floats
    float* scores = rec + (size_t)B * H;          // T*B floats
    float* pm     = scores + (size_t)T * B;       // NCH*B floats
    float* ps     = pm + (size_t)NCH * B;         // NCH*B floats
    float* out    = (float*)d_out;                // (T,B)

    // Kernel 1: B*H outputs, one wave each
    {
        int nOut   = B * H;
        int blocks = (nOut + 3) / 4;
        rec_kernel<<<blocks, 256, 0, stream>>>(rnn, Wrec, rec, B, H, R);
    }
    // Kernel 2: one block per 8-t chunk, 512 threads
    score_kernel<<<NCH, 512, 0, stream>>>(enc, mask, rec, wsc, bsc,
                                          scores, pm, ps, T, B, H);
    // Kernel 3: one block per 64-t range
    finalize_kernel<<<T / 64, 256, 0, stream>>>(scores, pm, ps, out, T, B, NCH);
}

// Round 11
// 63.738 us; speedup vs baseline: 1.3194x; 1.3194x over previous
//
#include <hip/hip_runtime.h>
#include <math.h>

typedef float vf4 __attribute__((ext_vector_type(4)));

__device__ __forceinline__ float wave_reduce_sum(float v) {
    #pragma unroll
    for (int off = 32; off > 0; off >>= 1)
        v += __shfl_xor(v, off, 64);
    return v;
}

// fast tanh: tanh(x) = 1 - 2/(exp(2x)+1); exp via v_exp, recip via v_rcp
__device__ __forceinline__ float fast_tanh(float x) {
    float e = __expf(2.0f * x);
    return 1.0f - 2.0f * __builtin_amdgcn_rcpf(e + 1.0f);
}

// Kernel 1: rec[b*H + h] = dot(rnn_state[b,:], W_rec[h,:])
__global__ void rec_kernel(const float* __restrict__ rnn,
                           const float* __restrict__ Wrec,
                           float* __restrict__ rec,
                           int B, int H, int R) {
    int w    = (blockIdx.x * blockDim.x + threadIdx.x) >> 6;
    int lane = threadIdx.x & 63;
    int nOut = B * H;
    if (w >= nOut) return;
    int b = w / H;
    int h = w - b * H;
    const float* xr = rnn  + (size_t)b * R;
    const float* wr = Wrec + (size_t)h * R;
    float acc = 0.f;
    for (int r = lane * 4; r < R; r += 256) {
        vf4 a = *(const vf4*)(xr + r);
        vf4 c = *(const vf4*)(wr + r);
        acc += a.x * c.x + a.y * c.y + a.z * c.z + a.w * c.w;
    }
    acc = wave_reduce_sum(acc);
    if (lane == 0) rec[w] = acc;
}

// Kernel 2 (R5-proven core + fused strip stats): each wave owns fixed b and
// 16 consecutive t. Per-row partials in acc[16]; one batched tree-reduce per
// strip; lanes 0..15 store scores coalesced into (B,T) AND emit this strip's
// softmax partial (max, expsum) -- the standalone stats pass is gone.
#define SCORE_ROWS 16
__global__ void score_kernel(const float* __restrict__ enc,
                             const float* __restrict__ mask,
                             const float* __restrict__ rec,
                             const float* __restrict__ wsc,
                             const float* __restrict__ bsc,
                             float* __restrict__ scores_t,  // (B,T)
                             float* __restrict__ pm,        // (B,NCH)
                             float* __restrict__ ps,        // (B,NCH)
                             int T, int B, int H, int NCH) {
    const int w    = (blockIdx.x * blockDim.x + threadIdx.x) >> 6;
    const int lane = threadIdx.x & 63;
    const int b     = w % B;
    const int chunk = w / B;
    const int tbase = chunk * SCORE_ROWS;
    if (tbase >= T) return;

    const int h0 = lane * 4;          // first half: h in [0, H/2)
    const int h1 = (H >> 1) + h0;     // second half

    const float* rr = rec + (size_t)b * H;
    vf4 r0 = *(const vf4*)(rr + h0);
    vf4 r1 = *(const vf4*)(rr + h1);
    vf4 w0 = *(const vf4*)(wsc + h0);
    vf4 w1 = *(const vf4*)(wsc + h1);
    const float bias = bsc[0];

    const float* erow = enc + ((size_t)tbase * B + b) * H;
    const size_t rstride = (size_t)B * H;

    float acc[SCORE_ROWS];
    #pragma unroll
    for (int i = 0; i < SCORE_ROWS; ++i) {
        const float* er = erow + (size_t)i * rstride;
        vf4 e0 = *(const vf4*)(er + h0);
        vf4 e1 = *(const vf4*)(er + h1);
        float a;
        a  = w0.x * fast_tanh(e0.x + r0.x);
        a += w0.y * fast_tanh(e0.y + r0.y);
        a += w0.z * fast_tanh(e0.z + r0.z);
        a += w0.w * fast_tanh(e0.w + r0.w);
        a += w1.x * fast_tanh(e1.x + r1.x);
        a += w1.y * fast_tanh(e1.y + r1.y);
        a += w1.z * fast_tanh(e1.z + r1.z);
        a += w1.w * fast_tanh(e1.w + r1.w);
        acc[i] = a;
    }

    // fold stages: 16 -> 8 -> 4 -> 2 -> 1 values across lane bits 0..3
    #pragma unroll
    for (int s = 0; s < 4; ++s) {
        const int bit = 1 << s;
        #pragma unroll
        for (int i = 0; i < (SCORE_ROWS >> (s + 1)); ++i) {
            float sent = (lane & bit) ? acc[2 * i]     : acc[2 * i + 1];
            float keep = (lane & bit) ? acc[2 * i + 1] : acc[2 * i];
            acc[i] = keep + __shfl_xor(sent, bit, 64);
        }
    }
    acc[0] += __shfl_xor(acc[0], 16, 64);
    acc[0] += __shfl_xor(acc[0], 32, 64);
    // every lane now holds the full row-sum for row (lane & 15)

    if (lane < SCORE_ROWS) {
        const int t = tbase + lane;
        float sc = acc[0] + bias + mask[(size_t)t * B + b];
        scores_t[(size_t)b * T + t] = sc;

        // strip softmax partial among lanes 0..15 (xor partners stay inside)
        float m = sc;
        m = fmaxf(m, __shfl_xor(m, 1, 64));
        m = fmaxf(m, __shfl_xor(m, 2, 64));
        m = fmaxf(m, __shfl_xor(m, 4, 64));
        m = fmaxf(m, __shfl_xor(m, 8, 64));
        float e = __expf(sc - m);
        e += __shfl_xor(e, 1, 64);
        e += __shfl_xor(e, 2, 64);
        e += __shfl_xor(e, 4, 64);
        e += __shfl_xor(e, 8, 64);
        if (lane == 0) {
            pm[(size_t)b * NCH + chunk] = m;
            ps[(size_t)b * NCH + chunk] = e;
        }
    }
}

// Kernel 3: finalize. Each block redundantly merges the NCH partials per b
// (slice-parallel: 8 slices x 32 b, per-thread reads are consecutive floats),
// then 64t x 32b tile: coalesced load from (B,T), LDS transpose (padded),
// exp(x-M)*Sinv, coalesced 128B stores to (T,B).
__global__ void finalize_kernel(const float* __restrict__ scores_t,
                                const float* __restrict__ pm,
                                const float* __restrict__ ps,
                                float* __restrict__ out,
                                int T, int B, int NCH) {
    __shared__ float red[8][32];
    __shared__ float Ml[32], Si[32];
    __shared__ float tile[32][65];
    const int tid = threadIdx.x;
    const int b   = tid & 31;
    const int sl  = tid >> 5;            // 0..7
    const int cps = NCH / 8;             // chunks per slice

    float m = -INFINITY;
    for (int c = sl * cps; c < (sl + 1) * cps; ++c)
        m = fmaxf(m, pm[(size_t)b * NCH + c]);
    red[sl][b] = m;
    __syncthreads();
    if (tid < 32) {
        float M = -INFINITY;
        #pragma unroll
        for (int s = 0; s < 8; ++s) M = fmaxf(M, red[s][tid]);
        Ml[tid] = M;
    }
    __syncthreads();
    const float M = Ml[b];
    float s = 0.f;
    for (int c = sl * cps; c < (sl + 1) * cps; ++c)
        s += ps[(size_t)b * NCH + c] * __expf(pm[(size_t)b * NCH + c] - M);
    __syncthreads();                     // done with red as max buffer
    red[sl][b] = s;
    __syncthreads();
    if (tid < 32) {
        float S = 0.f;
        #pragma unroll
        for (int s2 = 0; s2 < 8; ++s2) S += red[s2][tid];
        Si[tid] = 1.0f / S;
    }
    __syncthreads();

    const int t0 = blockIdx.x * 64;
    #pragma unroll
    for (int i = 0; i < 8; ++i) {
        int idx  = i * 256 + tid;
        int brow = idx >> 6;             // 0..31
        int tcol = idx & 63;             // 0..63
        tile[brow][tcol] = scores_t[(size_t)brow * T + t0 + tcol];
    }
    __syncthreads();

    #pragma unroll
    for (int i = 0; i < 8; ++i) {
        int idx  = i * 256 + tid;
        int trow = idx >> 5;             // 0..63
        int bcol = idx & 31;             // 0..31
        float x = tile[bcol][trow];
        out[(size_t)(t0 + trow) * B + bcol] = __expf(x - Ml[bcol]) * Si[bcol];
    }
}

extern "C" void kernel_launch(void* const* d_in, const int* in_sizes, int n_in,
                              void* d_out, int out_size, void* d_ws, size_t ws_size,
                              hipStream_t stream) {
    const float* enc  = (const float*)d_in[0];  // (T,B,H)
    const float* mask = (const float*)d_in[1];  // (T,B)
    const float* rnn  = (const float*)d_in[2];  // (B,R)
    // d_in[3] = prev_att_weights, unused by the reference
    const float* Wrec = (const float*)d_in[4];  // (H,R)
    const float* wsc  = (const float*)d_in[5];  // (H,)
    const float* bsc  = (const float*)d_in[6];  // (1,)

    const int H = in_sizes[5];
    const int R = in_sizes[4] / H;
    const int B = in_sizes[2] / R;
    const int T = in_sizes[1] / B;
    const int NCH = T / SCORE_ROWS;

    float* rec      = (float*)d_ws;                       // B*H floats
    float* scores_t = rec + (size_t)B * H;                // (B,T) floats
    float* pm       = scores_t + (size_t)B * T;           // B*NCH floats
    float* ps       = pm + (size_t)B * NCH;               // B*NCH floats
    float* out      = (float*)d_out;                      // (T,B)

    // Kernel 1: B*H outputs, one wave each
    {
        int nOut   = B * H;
        int blocks = (nOut + 3) / 4;
        rec_kernel<<<blocks, 256, 0, stream>>>(rnn, Wrec, rec, B, H, R);
    }
    // Kernel 2: one wave per (b, 16-row strip), fused strip stats
    {
        int nWaves = NCH * B;
        int blocks = (nWaves + 3) / 4;
        score_kernel<<<blocks, 256, 0, stream>>>(enc, mask, rec, wsc, bsc,
                                                 scores_t, pm, ps, T, B, H, NCH);
    }
    // Kernel 3: one block per 64-t tile
    finalize_kernel<<<T / 64, 256, 0, stream>>>(scores_t, pm, ps, out, T, B, NCH);
}

// Round 12
// 55.665 us; speedup vs baseline: 1.5107x; 1.1450x over previous
//
#include <hip/hip_runtime.h>
#include <math.h>

typedef float vf4 __attribute__((ext_vector_type(4)));

__device__ __forceinline__ float wave_reduce_sum(float v) {
    #pragma unroll
    for (int off = 32; off > 0; off >>= 1)
        v += __shfl_xor(v, off, 64);
    return v;
}
__device__ __forceinline__ float wave_reduce_max(float v) {
    #pragma unroll
    for (int off = 32; off > 0; off >>= 1)
        v = fmaxf(v, __shfl_xor(v, off, 64));
    return v;
}

// fast tanh: tanh(x) = 1 - 2/(exp(2x)+1); exp via v_exp, recip via v_rcp
__device__ __forceinline__ float fast_tanh(float x) {
    float e = __expf(2.0f * x);
    return 1.0f - 2.0f * __builtin_amdgcn_rcpf(e + 1.0f);
}

// Kernel 1: rec[b*H + h] = dot(rnn_state[b,:], W_rec[h,:])
// One wave per output element; lanes split R with float4 loads.
__global__ void rec_kernel(const float* __restrict__ rnn,
                           const float* __restrict__ Wrec,
                           float* __restrict__ rec,
                           int B, int H, int R) {
    int w    = (blockIdx.x * blockDim.x + threadIdx.x) >> 6;
    int lane = threadIdx.x & 63;
    int nOut = B * H;
    if (w >= nOut) return;
    int b = w / H;
    int h = w - b * H;
    const float* xr = rnn  + (size_t)b * R;
    const float* wr = Wrec + (size_t)h * R;
    float acc = 0.f;
    for (int r = lane * 4; r < R; r += 256) {
        vf4 a = *(const vf4*)(xr + r);
        vf4 c = *(const vf4*)(wr + r);
        acc += a.x * c.x + a.y * c.y + a.z * c.z + a.w * c.w;
    }
    acc = wave_reduce_sum(acc);
    if (lane == 0) rec[w] = acc;
}

// Kernel 2: each wave owns a fixed b and SCORE_ROWS consecutive t values.
// Per-row partials in acc[16]; one batched tree-reduce per strip (17 shfls)
// replaces 16 serial 6-step butterflies; lanes 0..15 do one coalesced
// 16-lane store into (B,T) scores.
#define SCORE_ROWS 16
__global__ void score_kernel(const float* __restrict__ enc,
                             const float* __restrict__ mask,
                             const float* __restrict__ rec,
                             const float* __restrict__ wsc,
                             const float* __restrict__ bsc,
                             float* __restrict__ scores_t,  // (B,T)
                             int T, int B, int H) {
    const int w    = (blockIdx.x * blockDim.x + threadIdx.x) >> 6;
    const int lane = threadIdx.x & 63;
    const int b     = w % B;
    const int tbase = (w / B) * SCORE_ROWS;
    if (tbase >= T) return;

    const int h0 = lane * 4;          // first half: h in [0, H/2)
    const int h1 = (H >> 1) + h0;     // second half

    const float* rr = rec + (size_t)b * H;
    vf4 r0 = *(const vf4*)(rr + h0);
    vf4 r1 = *(const vf4*)(rr + h1);
    vf4 w0 = *(const vf4*)(wsc + h0);
    vf4 w1 = *(const vf4*)(wsc + h1);
    const float bias = bsc[0];

    const float* erow = enc + ((size_t)tbase * B + b) * H;
    const size_t rstride = (size_t)B * H;

    float acc[SCORE_ROWS];
    #pragma unroll
    for (int i = 0; i < SCORE_ROWS; ++i) {
        const float* er = erow + (size_t)i * rstride;
        vf4 e0 = *(const vf4*)(er + h0);
        vf4 e1 = *(const vf4*)(er + h1);
        float a;
        a  = w0.x * fast_tanh(e0.x + r0.x);
        a += w0.y * fast_tanh(e0.y + r0.y);
        a += w0.z * fast_tanh(e0.z + r0.z);
        a += w0.w * fast_tanh(e0.w + r0.w);
        a += w1.x * fast_tanh(e1.x + r1.x);
        a += w1.y * fast_tanh(e1.y + r1.y);
        a += w1.z * fast_tanh(e1.z + r1.z);
        a += w1.w * fast_tanh(e1.w + r1.w);
        acc[i] = a;
    }

    // fold stages: 16 -> 8 -> 4 -> 2 -> 1 values across lane bits 0..3
    #pragma unroll
    for (int s = 0; s < 4; ++s) {
        const int bit = 1 << s;
        #pragma unroll
        for (int i = 0; i < (SCORE_ROWS >> (s + 1)); ++i) {
            float sent = (lane & bit) ? acc[2 * i]     : acc[2 * i + 1];
            float keep = (lane & bit) ? acc[2 * i + 1] : acc[2 * i];
            acc[i] = keep + __shfl_xor(sent, bit, 64);
        }
    }
    // finish the 64-lane sum: lane l now owns row (l&15)
    acc[0] += __shfl_xor(acc[0], 16, 64);
    acc[0] += __shfl_xor(acc[0], 32, 64);

    if (lane < SCORE_ROWS) {
        const int t = tbase + lane;
        scores_t[(size_t)b * T + t] = acc[0] + bias + mask[(size_t)t * B + b];
    }
}

// Kernel 3: softmax over T per column b. One block (T/4 threads) per b.
// Coalesced float4 read from (B,T) scores; scattered 4B writes to (T,B) out.
__global__ void softmax_kernel(const float* __restrict__ scores_t,
                               float* __restrict__ out, int T, int B) {
    const int b    = blockIdx.x;
    const int tid  = threadIdx.x;
    const int wid  = tid >> 6;
    const int lane = tid & 63;
    const int nw   = blockDim.x >> 6;

    vf4 v = *(const vf4*)(scores_t + (size_t)b * T + tid * 4);

    __shared__ float red[16];

    float m = fmaxf(fmaxf(v.x, v.y), fmaxf(v.z, v.w));
    m = wave_reduce_max(m);
    if (lane == 0) red[wid] = m;
    __syncthreads();
    if (tid < 64) {
        float mm = (tid < nw) ? red[tid] : -INFINITY;
        mm = wave_reduce_max(mm);
        if (tid == 0) red[0] = mm;
    }
    __syncthreads();
    m = red[0];
    __syncthreads();                 // everyone has read red[0]

    v.x = __expf(v.x - m);
    v.y = __expf(v.y - m);
    v.z = __expf(v.z - m);
    v.w = __expf(v.w - m);
    float s = (v.x + v.y) + (v.z + v.w);
    s = wave_reduce_sum(s);
    if (lane == 0) red[wid] = s;
    __syncthreads();
    if (tid < 64) {
        float ss = (tid < nw) ? red[tid] : 0.f;
        ss = wave_reduce_sum(ss);
        if (tid == 0) red[0] = ss;
    }
    __syncthreads();
    const float inv = 1.0f / red[0];

    const int t0 = tid * 4;
    out[(size_t)(t0 + 0) * B + b] = v.x * inv;
    out[(size_t)(t0 + 1) * B + b] = v.y * inv;
    out[(size_t)(t0 + 2) * B + b] = v.z * inv;
    out[(size_t)(t0 + 3) * B + b] = v.w * inv;
}

extern "C" void kernel_launch(void* const* d_in, const int* in_sizes, int n_in,
                              void* d_out, int out_size, void* d_ws, size_t ws_size,
                              hipStream_t stream) {
    const float* enc  = (const float*)d_in[0];  // (T,B,H)
    const float* mask = (const float*)d_in[1];  // (T,B)
    const float* rnn  = (const float*)d_in[2];  // (B,R)
    // d_in[3] = prev_att_weights, unused by the reference
    const float* Wrec = (const float*)d_in[4];  // (H,R)
    const float* wsc  = (const float*)d_in[5];  // (H,)
    const float* bsc  = (const float*)d_in[6];  // (1,)

    const int H = in_sizes[5];
    const int R = in_sizes[4] / H;
    const int B = in_sizes[2] / R;
    const int T = in_sizes[1] / B;

    float* rec      = (float*)d_ws;                  // B*H floats (64 KB)
    float* scores_t = rec + (size_t)B * H;           // (B,T) floats (512 KB)
    float* out      = (float*)d_out;                 // (T,B)

    // Kernel 1: B*H outputs, one wave each, 4 waves per 256-thread block
    {
        int nOut   = B * H;
        int blocks = (nOut + 3) / 4;
        rec_kernel<<<blocks, 256, 0, stream>>>(rnn, Wrec, rec, B, H, R);
    }
    // Kernel 2: one wave per (b, 16-row strip): T*B/16 waves
    {
        int nWaves = (T / SCORE_ROWS) * B;
        int blocks = (nWaves + 3) / 4;
        score_kernel<<<blocks, 256, 0, stream>>>(enc, mask, rec, wsc, bsc,
                                                 scores_t, T, B, H);
    }
    // Kernel 3: one block per b, T/4 threads (T=4096 -> 1024)
    softmax_kernel<<<B, T / 4, 0, stream>>>(scores_t, out, T, B);
}